// Round 6
// baseline (231.272 us; speedup 1.0000x reference)
//
#include <hip/hip_runtime.h>
#include <math.h>

#define H   2048
#define SW  256
#define SD  200
#define GIN (H + SW)   // 2304
#define G3H (3 * H)    // 6144
#define OO  128

// ws float offsets
#define STOP_OFF 8                  // stack_top, 256 floats
#define GIE_OFF  512                // gi_emb = W_ih[:,:H]@x + b_ih, 6144 floats
#define GH_OFF   (GIE_OFF + G3H)    // gh, 6144 floats

// K1 block partition (no intra-kernel dependencies anywhere)
#define NB_GIE  384
#define NB_GH   384
#define NB_SIN  64
#define NB_ELEM 50
#define B_GH    NB_GIE                    // 384
#define B_SIN   (B_GH + NB_GH)            // 768
#define B_ELEM  (B_SIN + NB_SIN)          // 832
#define NBLK1   (B_ELEM + NB_ELEM)        // 882

__device__ __forceinline__ float wave_reduce(float v) {
#pragma unroll
    for (int off = 32; off > 0; off >>= 1)
        v += __shfl_down(v, off, 64);
    return v;
}

__device__ __forceinline__ float sigmoidf(float x) {
    return 1.f / (1.f + expf(-x));
}

__device__ __forceinline__ float dot4(float4 a, float4 b) {
    return a.x * b.x + a.y * b.y + a.z * b.z + a.w * b.w;
}

// K1: everything with no mutual dependency:
//  blocks [0,384):    gi_emb rows (16/block), K=2048 over x=emb[inp]
//  blocks [384,768):  gh rows (16/block),     K=2048 over hidden
//  blocks [768,832):  ctrl + s_in rows (4/block) + stack_top -> ws & d_out
//  blocks [832,882):  new_stack rows 1..199 elementwise -> d_out
__global__ __launch_bounds__(256, 4) void k_main(
        const float* __restrict__ hidden,
        const float* __restrict__ stack,
        const float* __restrict__ emb,
        const int*   __restrict__ inp,
        const float* __restrict__ Wc, const float* __restrict__ bc,
        const float* __restrict__ Ws, const float* __restrict__ bs,
        const float* __restrict__ W_ih, const float* __restrict__ b_ih,
        const float* __restrict__ W_hh, const float* __restrict__ b_hh,
        float* __restrict__ ws,
        float* __restrict__ d_out) {
    __shared__ __align__(16) float lds[H];
    float* out_stack = d_out + OO + H;
    int b = blockIdx.x;
    int tid = threadIdx.x;
    int wave = tid >> 6, lane = tid & 63;

    if (b < B_SIN) {
        // ---- GEMV halves: uniform K=2048 dot, 4 rows/wave, x2-unrolled ----
        bool is_gie = (b < B_GH);
        int idx = is_gie ? b : (b - B_GH);
        const float* srcv = is_gie ? (emb + (long)inp[0] * H) : hidden;
        {   // stage 2048-float vector to LDS
            float4* l4 = (float4*)lds;
            const float4* s4 = (const float4*)srcv;
            l4[tid] = s4[tid];
            l4[tid + 256] = s4[tid + 256];
        }
        __syncthreads();
        int rbase = idx * 16 + wave * 4;
        long stride4 = is_gie ? (GIN / 4) : (H / 4);  // float4 row stride
        const float* W    = is_gie ? W_ih : W_hh;
        const float* bias = is_gie ? b_ih : b_hh;
        const float4* v4 = (const float4*)lds;
        const float4* w0 = (const float4*)W + (rbase + 0) * stride4;
        const float4* w1 = (const float4*)W + (rbase + 1) * stride4;
        const float4* w2 = (const float4*)W + (rbase + 2) * stride4;
        const float4* w3 = (const float4*)W + (rbase + 3) * stride4;
        float s0 = 0.f, s1 = 0.f, s2 = 0.f, s3 = 0.f;
#pragma unroll
        for (int u = 0; u < 4; ++u) {       // 512 float4s, x2 pairs -> 8 loads in flight
            int i = lane + u * 128, j = i + 64;
            float4 a0 = v4[i], a1 = v4[j];
            float4 b00 = w0[i], b01 = w0[j];
            float4 b10 = w1[i], b11 = w1[j];
            float4 b20 = w2[i], b21 = w2[j];
            float4 b30 = w3[i], b31 = w3[j];
            s0 += dot4(a0, b00) + dot4(a1, b01);
            s1 += dot4(a0, b10) + dot4(a1, b11);
            s2 += dot4(a0, b20) + dot4(a1, b21);
            s3 += dot4(a0, b30) + dot4(a1, b31);
        }
        s0 = wave_reduce(s0);
        s1 = wave_reduce(s1);
        s2 = wave_reduce(s2);
        s3 = wave_reduce(s3);
        float* dst = ws + (is_gie ? GIE_OFF : GH_OFF);
        if (lane == 0) {
            dst[rbase + 0] = s0 + bias[rbase + 0];
            dst[rbase + 1] = s1 + bias[rbase + 1];
            dst[rbase + 2] = s2 + bias[rbase + 2];
            dst[rbase + 3] = s3 + bias[rbase + 3];
        }
        return;
    }

    // ---- stack roles: ctrl softmax (redundant per block, L2-hot) ----
    if (tid < 64) {
        float c0 = 0.f, c1 = 0.f, c2 = 0.f;
        for (int k = tid; k < H; k += 64) {
            float hv = hidden[k];
            c0 += hv * Wc[k];
            c1 += hv * Wc[H + k];
            c2 += hv * Wc[2 * H + k];
        }
        c0 = wave_reduce(c0); c1 = wave_reduce(c1); c2 = wave_reduce(c2);
        if (tid == 0) {
            c0 += bc[0]; c1 += bc[1]; c2 += bc[2];
            float m = fmaxf(c0, fmaxf(c1, c2));
            float e0 = expf(c0 - m), e1 = expf(c1 - m), e2 = expf(c2 - m);
            float inv = 1.f / (e0 + e1 + e2);
            lds[0] = e0 * inv;  // push
            lds[1] = e1 * inv;  // pop
            lds[2] = e2 * inv;  // noop
        }
    }
    __syncthreads();
    float a_push = lds[0], a_pop = lds[1], a_noop = lds[2];
    if (b < B_ELEM) {
        // ---- s_in rows (1/wave) + new_stack row 0 + stack_top ----
        int row = (b - B_SIN) * 4 + wave;
        const float4* h4 = (const float4*)hidden;
        const float4* w4 = (const float4*)(Ws + row * H);
        float sum = 0.f;
#pragma unroll
        for (int i = 0; i < 8; ++i)
            sum += dot4(h4[lane + i * 64], w4[lane + i * 64]);
        sum = wave_reduce(sum);
        if (lane == 0) {
            float s = tanhf(sum + bs[row]);
            float top = a_noop * stack[row] + a_push * s + a_pop * stack[SW + row];
            ws[STOP_OFF + row] = top;
            out_stack[row] = top;
        }
    } else {
        // ---- new_stack rows 1..199 elementwise ----
        int rbase = 1 + (b - B_ELEM) * 4;
#pragma unroll
        for (int r = 0; r < 4; ++r) {
            int row = rbase + r;
            if (row >= SD) break;
            int idx = row * SW + tid;
            float dn = (row < SD - 1) ? stack[idx + SW] : 0.f;
            out_stack[idx] = a_noop * stack[idx] + a_push * stack[idx - SW] + a_pop * dn;
        }
    }
}

// K2: 32 blocks; block b owns h-slice [b*64, b*64+64).
//  phase 1: gi correction gs[g*64+j] = gi_emb[row] + W_ih[row, 2048:]@stack_top
//           (192 disjoint rows/block, 48/wave, coalesced 64-float4 dots)
//  phase 2: gates -> h_new slice -> d_out[OO+...] + LDS
//  phase 3: out partials via Wd columns, atomicAdd into pre-zeroed d_out[0:128]
__global__ __launch_bounds__(256, 4) void k_out(
        const float* __restrict__ hidden,
        const float* __restrict__ W_ih,
        const float* __restrict__ Wd, const float* __restrict__ bd,
        const float* __restrict__ ws,
        float* __restrict__ d_out) {
    __shared__ __align__(16) float st[SW];   // stack_top
    __shared__ float gs[192];                // full gi for this slice (3 gates x 64)
    __shared__ float hn[64];                 // h_new slice
    int b = blockIdx.x;                      // 0..31
    int tid = threadIdx.x;
    int wave = tid >> 6, lane = tid & 63;
    if (tid < 64)
        ((float4*)st)[tid] = ((const float4*)(ws + STOP_OFF))[tid];
    __syncthreads();
    const float4* st4 = (const float4*)st;
#pragma unroll
    for (int t = 0; t < 48; ++t) {
        int fr = wave * 48 + t;              // flattened g*64+j
        int g = fr >> 6, j = fr & 63;
        int row = g * H + b * 64 + j;
        const float4* w4 = (const float4*)(W_ih + (long)row * GIN + H);
        float s = dot4(st4[lane], w4[lane]);
        s = wave_reduce(s);
        if (lane == 0) gs[fr] = s + ws[GIE_OFF + row];
    }
    __syncthreads();
    if (tid < 64) {
        int i = b * 64 + tid;
        float gir = gs[tid], giz = gs[64 + tid], gin = gs[128 + tid];
        float ghr = ws[GH_OFF + i];
        float ghz = ws[GH_OFF + H + i];
        float ghn = ws[GH_OFF + 2 * H + i];
        float r = sigmoidf(gir + ghr);
        float z = sigmoidf(giz + ghz);
        float n = tanhf(gin + r * ghn);
        float v = (1.f - z) * n + z * hidden[i];
        hn[tid] = v;
        d_out[OO + i] = v;
    }
    __syncthreads();
#pragma unroll
    for (int t = 0; t < 32; ++t) {
        int o = wave * 32 + t;               // 128 outputs
        float p = Wd[(long)o * H + b * 64 + lane] * hn[lane];
        p = wave_reduce(p);
        if (lane == 0) {
            float add = p + (b == 0 ? bd[o] : 0.f);
            atomicAdd(&d_out[o], add);
        }
    }
}

extern "C" void kernel_launch(void* const* d_in, const int* in_sizes, int n_in,
                              void* d_out, int out_size, void* d_ws, size_t ws_size,
                              hipStream_t stream) {
    const int*   inp    = (const int*)d_in[0];
    const float* hidden = (const float*)d_in[1];
    const float* stack  = (const float*)d_in[2];
    const float* emb    = (const float*)d_in[3];
    const float* Wc     = (const float*)d_in[4];
    const float* bc     = (const float*)d_in[5];
    const float* Ws     = (const float*)d_in[6];
    const float* bs     = (const float*)d_in[7];
    const float* W_ih   = (const float*)d_in[8];
    const float* b_ih   = (const float*)d_in[9];
    const float* W_hh   = (const float*)d_in[10];
    const float* b_hh   = (const float*)d_in[11];
    const float* Wd     = (const float*)d_in[12];
    const float* bd     = (const float*)d_in[13];
    float* out = (float*)d_out;
    float* ws  = (float*)d_ws;

    // d_out is poisoned 0xAA: zero the 128 atomicAdd accumulators
    hipMemsetAsync(out, 0, OO * sizeof(float), stream);
    k_main<<<NBLK1, 256, 0, stream>>>(hidden, stack, emb, inp, Wc, bc, Ws, bs,
                                      W_ih, b_ih, W_hh, b_hh, ws, out);
    k_out<<<32, 256, 0, stream>>>(hidden, W_ih, Wd, bd, ws, out);
}

// Round 7
// 192.194 us; speedup vs baseline: 1.2033x; 1.2033x over previous
//
#include <hip/hip_runtime.h>
#include <math.h>

#define H   2048
#define SW  256
#define SD  200
#define GIN (H + SW)   // 2304
#define G3H (3 * H)    // 6144
#define OO  128

// ws float offsets
#define STOP_OFF 8                  // stack_top, 256 floats
#define GIE_OFF  512                // gi_emb = W_ih[:,:H]@x + b_ih, 6144 floats
#define GH_OFF   (GIE_OFF + G3H)    // gh, 6144 floats

// K1 block partition (no intra-kernel dependencies anywhere)
#define NB_GIE  384
#define NB_GH   384
#define NB_SIN  64
#define NB_ELEM 50
#define B_GH    NB_GIE                    // 384
#define B_SIN   (B_GH + NB_GH)            // 768
#define B_ELEM  (B_SIN + NB_SIN)          // 832
#define NBLK1   (B_ELEM + NB_ELEM)        // 882

__device__ __forceinline__ float wave_reduce(float v) {
#pragma unroll
    for (int off = 32; off > 0; off >>= 1)
        v += __shfl_down(v, off, 64);
    return v;
}

__device__ __forceinline__ float sigmoidf(float x) {
    return 1.f / (1.f + expf(-x));
}

__device__ __forceinline__ float dot4(float4 a, float4 b) {
    return a.x * b.x + a.y * b.y + a.z * b.z + a.w * b.w;
}

// K1: everything with no mutual dependency:
//  blocks [0,384):    gi_emb rows (16/block), K=2048 over x=emb[inp]
//  blocks [384,768):  gh rows (16/block),     K=2048 over hidden
//  blocks [768,832):  ctrl + s_in rows (4/block) + stack_top -> ws & d_out
//  blocks [832,882):  new_stack rows 1..199 elementwise -> d_out
__global__ __launch_bounds__(256, 4) void k_main(
        const float* __restrict__ hidden,
        const float* __restrict__ stack,
        const float* __restrict__ emb,
        const int*   __restrict__ inp,
        const float* __restrict__ Wc, const float* __restrict__ bc,
        const float* __restrict__ Ws, const float* __restrict__ bs,
        const float* __restrict__ W_ih, const float* __restrict__ b_ih,
        const float* __restrict__ W_hh, const float* __restrict__ b_hh,
        float* __restrict__ ws,
        float* __restrict__ d_out) {
    __shared__ __align__(16) float lds[H];
    float* out_stack = d_out + OO + H;
    int b = blockIdx.x;
    int tid = threadIdx.x;
    int wave = tid >> 6, lane = tid & 63;

    if (b < B_SIN) {
        // ---- GEMV halves: uniform K=2048 dot, 4 rows/wave, x2-unrolled ----
        bool is_gie = (b < B_GH);
        int idx = is_gie ? b : (b - B_GH);
        const float* srcv = is_gie ? (emb + (long)inp[0] * H) : hidden;
        {   // stage 2048-float vector to LDS
            float4* l4 = (float4*)lds;
            const float4* s4 = (const float4*)srcv;
            l4[tid] = s4[tid];
            l4[tid + 256] = s4[tid + 256];
        }
        __syncthreads();
        int rbase = idx * 16 + wave * 4;
        long stride4 = is_gie ? (GIN / 4) : (H / 4);  // float4 row stride
        const float* W    = is_gie ? W_ih : W_hh;
        const float* bias = is_gie ? b_ih : b_hh;
        const float4* v4 = (const float4*)lds;
        const float4* w0 = (const float4*)W + (rbase + 0) * stride4;
        const float4* w1 = (const float4*)W + (rbase + 1) * stride4;
        const float4* w2 = (const float4*)W + (rbase + 2) * stride4;
        const float4* w3 = (const float4*)W + (rbase + 3) * stride4;
        float s0 = 0.f, s1 = 0.f, s2 = 0.f, s3 = 0.f;
#pragma unroll
        for (int u = 0; u < 4; ++u) {       // 512 float4s, x2 pairs -> 8 loads in flight
            int i = lane + u * 128, j = i + 64;
            float4 a0 = v4[i], a1 = v4[j];
            float4 b00 = w0[i], b01 = w0[j];
            float4 b10 = w1[i], b11 = w1[j];
            float4 b20 = w2[i], b21 = w2[j];
            float4 b30 = w3[i], b31 = w3[j];
            s0 += dot4(a0, b00) + dot4(a1, b01);
            s1 += dot4(a0, b10) + dot4(a1, b11);
            s2 += dot4(a0, b20) + dot4(a1, b21);
            s3 += dot4(a0, b30) + dot4(a1, b31);
        }
        s0 = wave_reduce(s0);
        s1 = wave_reduce(s1);
        s2 = wave_reduce(s2);
        s3 = wave_reduce(s3);
        float* dst = ws + (is_gie ? GIE_OFF : GH_OFF);
        if (lane == 0) {
            dst[rbase + 0] = s0 + bias[rbase + 0];
            dst[rbase + 1] = s1 + bias[rbase + 1];
            dst[rbase + 2] = s2 + bias[rbase + 2];
            dst[rbase + 3] = s3 + bias[rbase + 3];
        }
        return;
    }

    // ---- stack roles: ctrl softmax (redundant per block, L2-hot) ----
    if (tid < 64) {
        float c0 = 0.f, c1 = 0.f, c2 = 0.f;
        for (int k = tid; k < H; k += 64) {
            float hv = hidden[k];
            c0 += hv * Wc[k];
            c1 += hv * Wc[H + k];
            c2 += hv * Wc[2 * H + k];
        }
        c0 = wave_reduce(c0); c1 = wave_reduce(c1); c2 = wave_reduce(c2);
        if (tid == 0) {
            c0 += bc[0]; c1 += bc[1]; c2 += bc[2];
            float m = fmaxf(c0, fmaxf(c1, c2));
            float e0 = expf(c0 - m), e1 = expf(c1 - m), e2 = expf(c2 - m);
            float inv = 1.f / (e0 + e1 + e2);
            lds[0] = e0 * inv;  // push
            lds[1] = e1 * inv;  // pop
            lds[2] = e2 * inv;  // noop
        }
    }
    __syncthreads();
    float a_push = lds[0], a_pop = lds[1], a_noop = lds[2];
    if (b < B_ELEM) {
        // ---- s_in rows (1/wave) + new_stack row 0 + stack_top ----
        int row = (b - B_SIN) * 4 + wave;
        const float4* h4 = (const float4*)hidden;
        const float4* w4 = (const float4*)(Ws + row * H);
        float sum = 0.f;
#pragma unroll
        for (int i = 0; i < 8; ++i)
            sum += dot4(h4[lane + i * 64], w4[lane + i * 64]);
        sum = wave_reduce(sum);
        if (lane == 0) {
            float s = tanhf(sum + bs[row]);
            float top = a_noop * stack[row] + a_push * s + a_pop * stack[SW + row];
            ws[STOP_OFF + row] = top;
            out_stack[row] = top;
        }
    } else {
        // ---- new_stack rows 1..199 elementwise ----
        int rbase = 1 + (b - B_ELEM) * 4;
#pragma unroll
        for (int r = 0; r < 4; ++r) {
            int row = rbase + r;
            if (row >= SD) break;
            int idx = row * SW + tid;
            float dn = (row < SD - 1) ? stack[idx + SW] : 0.f;
            out_stack[idx] = a_noop * stack[idx] + a_push * stack[idx - SW] + a_pop * dn;
        }
    }
}

// K2 v2: 32 blocks; block b owns h-slice [b*64, b*64+64). MLP everywhere:
//  phase 0: stack_top (LDS) + gie slice (LDS, coalesced)
//  phase 1: gi corrections, 4 rows in flight per wave (12 iters of 4)
//  phase 2: gates -> h_new slice -> d_out[OO+...] + LDS
//  phase 3: Wd partials, 4 outputs in flight per wave, atomicAdd (pre-zeroed)
__global__ __launch_bounds__(256, 4) void k_out(
        const float* __restrict__ hidden,
        const float* __restrict__ W_ih,
        const float* __restrict__ Wd, const float* __restrict__ bd,
        const float* __restrict__ ws,
        float* __restrict__ d_out) {
    __shared__ __align__(16) float st[SW];   // stack_top
    __shared__ float gs[192];                // gi for this slice (3 gates x 64)
    __shared__ float hn[64];                 // h_new slice
    int b = blockIdx.x;                      // 0..31
    int tid = threadIdx.x;
    int wave = tid >> 6, lane = tid & 63;
    if (tid < 64)
        ((float4*)st)[tid] = ((const float4*)(ws + STOP_OFF))[tid];
    if (tid < 192)                           // preload gi_emb slice (3 x 64 coalesced)
        gs[tid] = ws[GIE_OFF + (tid >> 6) * H + b * 64 + (tid & 63)];
    __syncthreads();
    const float4* st4 = (const float4*)st;
    float4 a = st4[lane];
#pragma unroll
    for (int t = 0; t < 12; ++t) {           // 48 rows/wave, 4 in flight
        int fr = wave * 48 + t * 4;          // flattened g*64+j
        const float* base0 = W_ih + (long)(((fr + 0) >> 6) * H + b * 64 + ((fr + 0) & 63)) * GIN + H;
        const float* base1 = W_ih + (long)(((fr + 1) >> 6) * H + b * 64 + ((fr + 1) & 63)) * GIN + H;
        const float* base2 = W_ih + (long)(((fr + 2) >> 6) * H + b * 64 + ((fr + 2) & 63)) * GIN + H;
        const float* base3 = W_ih + (long)(((fr + 3) >> 6) * H + b * 64 + ((fr + 3) & 63)) * GIN + H;
        float4 w0 = ((const float4*)base0)[lane];
        float4 w1 = ((const float4*)base1)[lane];
        float4 w2 = ((const float4*)base2)[lane];
        float4 w3 = ((const float4*)base3)[lane];
        float s0 = wave_reduce(dot4(a, w0));
        float s1 = wave_reduce(dot4(a, w1));
        float s2 = wave_reduce(dot4(a, w2));
        float s3 = wave_reduce(dot4(a, w3));
        if (lane == 0) {
            gs[fr + 0] += s0;
            gs[fr + 1] += s1;
            gs[fr + 2] += s2;
            gs[fr + 3] += s3;
        }
    }
    __syncthreads();
    if (tid < 64) {
        int i = b * 64 + tid;
        float gir = gs[tid], giz = gs[64 + tid], gin = gs[128 + tid];
        float ghr = ws[GH_OFF + i];
        float ghz = ws[GH_OFF + H + i];
        float ghn = ws[GH_OFF + 2 * H + i];
        float r = sigmoidf(gir + ghr);
        float z = sigmoidf(giz + ghz);
        float n = tanhf(gin + r * ghn);
        float v = (1.f - z) * n + z * hidden[i];
        hn[tid] = v;
        d_out[OO + i] = v;
    }
    __syncthreads();
    float h = hn[lane];
    long col = (long)b * 64 + lane;
#pragma unroll
    for (int t = 0; t < 8; ++t) {            // 32 outputs/wave, 4 in flight
        int o = wave * 32 + t * 4;
        float p0 = wave_reduce(Wd[(long)(o + 0) * H + col] * h);
        float p1 = wave_reduce(Wd[(long)(o + 1) * H + col] * h);
        float p2 = wave_reduce(Wd[(long)(o + 2) * H + col] * h);
        float p3 = wave_reduce(Wd[(long)(o + 3) * H + col] * h);
        if (lane == 0) {
            atomicAdd(&d_out[o + 0], p0 + (b == 0 ? bd[o + 0] : 0.f));
            atomicAdd(&d_out[o + 1], p1 + (b == 0 ? bd[o + 1] : 0.f));
            atomicAdd(&d_out[o + 2], p2 + (b == 0 ? bd[o + 2] : 0.f));
            atomicAdd(&d_out[o + 3], p3 + (b == 0 ? bd[o + 3] : 0.f));
        }
    }
}

extern "C" void kernel_launch(void* const* d_in, const int* in_sizes, int n_in,
                              void* d_out, int out_size, void* d_ws, size_t ws_size,
                              hipStream_t stream) {
    const int*   inp    = (const int*)d_in[0];
    const float* hidden = (const float*)d_in[1];
    const float* stack  = (const float*)d_in[2];
    const float* emb    = (const float*)d_in[3];
    const float* Wc     = (const float*)d_in[4];
    const float* bc     = (const float*)d_in[5];
    const float* Ws     = (const float*)d_in[6];
    const float* bs     = (const float*)d_in[7];
    const float* W_ih   = (const float*)d_in[8];
    const float* b_ih   = (const float*)d_in[9];
    const float* W_hh   = (const float*)d_in[10];
    const float* b_hh   = (const float*)d_in[11];
    const float* Wd     = (const float*)d_in[12];
    const float* bd     = (const float*)d_in[13];
    float* out = (float*)d_out;
    float* ws  = (float*)d_ws;

    // d_out is poisoned 0xAA: zero the 128 atomicAdd accumulators
    hipMemsetAsync(out, 0, OO * sizeof(float), stream);
    k_main<<<NBLK1, 256, 0, stream>>>(hidden, stack, emb, inp, Wc, bc, Ws, bs,
                                      W_ih, b_ih, W_hh, b_hh, ws, out);
    k_out<<<32, 256, 0, stream>>>(hidden, W_ih, Wd, bd, ws, out);
}